// Round 1
// baseline (122.657 us; speedup 1.0000x reference)
//
#include <hip/hip_runtime.h>
#include <math.h>

// Problem constants (match reference)
#define BB 16384
#define TT 99
#define EE 10
#define RR 10
#define LL 3

// tanh(x) = 1 - 2/(exp(2x)+1); exact limits at +-inf (no inf/inf NaN).
__device__ __forceinline__ float fast_tanh(float x) {
    float e = __expf(2.0f * x);
    return fmaf(-2.0f, __builtin_amdgcn_rcpf(e + 1.0f), 1.0f);
}

// One thread per batch row. block=64 -> one wave per block, 256 blocks -> 1 wave/CU.
__global__ __launch_bounds__(64, 1)
void rnn_fused_kernel(const int* __restrict__ tok_ids,
                      const float* __restrict__ labels,
                      const float* __restrict__ emb,
                      const float* __restrict__ W,
                      const float* __restrict__ U,
                      const float* __restrict__ bvec,
                      const float* __restrict__ Wo,
                      const float* __restrict__ bo,
                      float* __restrict__ states_out,
                      float* __restrict__ probs_out,
                      float* __restrict__ ws)
{
    const int b = blockIdx.x * 64 + threadIdx.x;

    // --- uniform small weights -> per-lane registers ---
    float Ur[RR][RR];
#pragma unroll
    for (int i = 0; i < RR; ++i)
#pragma unroll
        for (int j = 0; j < RR; ++j)
            Ur[i][j] = U[i * RR + j];

    // c[tok][j] = b[j] + emb[tok] . W[:,j]  for tok in {1,2} (tok 0 is masked)
    float c1[RR], c2[RR];
#pragma unroll
    for (int j = 0; j < RR; ++j) { c1[j] = bvec[j]; c2[j] = bvec[j]; }
#pragma unroll
    for (int i = 0; i < EE; ++i) {
        float e1 = emb[1 * EE + i];
        float e2 = emb[2 * EE + i];
#pragma unroll
        for (int j = 0; j < RR; ++j) {
            float w = W[i * RR + j];
            c1[j] = fmaf(e1, w, c1[j]);
            c2[j] = fmaf(e2, w, c2[j]);
        }
    }

    float Wor[RR][LL];
#pragma unroll
    for (int j = 0; j < RR; ++j)
#pragma unroll
        for (int l = 0; l < LL; ++l)
            Wor[j][l] = Wo[j * LL + l];
    const float bo0 = bo[0], bo1 = bo[1], bo2 = bo[2];

    float h[RR];
#pragma unroll
    for (int j = 0; j < RR; ++j) h[j] = 0.0f;

    const int*   trow = tok_ids    + (size_t)b * TT;
    const float* lrow = labels     + (size_t)b * TT * LL;
    float*       srow = states_out + (size_t)b * TT * RR;
    float*       prow = probs_out  + (size_t)b * TT * LL;

    float loss_acc = 0.0f;
    int corr = 0;

    // prefetch t=0 inputs
    int   tk_cur = trow[0];
    float la1 = lrow[1], la2 = lrow[2];   // label one-hot; slot 0 inferred

#pragma unroll 1
    for (int t = 0; t < TT; ++t) {
        // prefetch next step's token + labels (clamped; hides latency under compute)
        const int tn = (t + 1 < TT) ? (t + 1) : (TT - 1);
        const int   tk_nxt = trow[tn];
        const float lb1n = lrow[tn * LL + 1];
        const float lb2n = lrow[tn * LL + 2];

        const int tk = tk_cur;
        const bool is1  = (tk == 1);
        const bool live = (tk != 0);

        float a[RR];
#pragma unroll
        for (int j = 0; j < RR; ++j) a[j] = is1 ? c1[j] : c2[j];
#pragma unroll
        for (int i = 0; i < RR; ++i) {
            const float hi = h[i];
#pragma unroll
            for (int j = 0; j < RR; ++j)
                a[j] = fmaf(hi, Ur[i][j], a[j]);
        }
#pragma unroll
        for (int j = 0; j < RR; ++j) {
            float hn = fast_tanh(a[j]);
            h[j] = live ? hn : h[j];     // Keras masking: masked step carries h
        }

        // states store: (b*T+t)*10 floats -> always 8B aligned, use float2 pairs
#pragma unroll
        for (int j = 0; j < RR; j += 2) {
            *reinterpret_cast<float2*>(srow + t * RR + j) = make_float2(h[j], h[j + 1]);
        }

        // dense (10x3) + softmax over 3
        float l0 = bo0, l1 = bo1, l2 = bo2;
#pragma unroll
        for (int j = 0; j < RR; ++j) {
            l0 = fmaf(h[j], Wor[j][0], l0);
            l1 = fmaf(h[j], Wor[j][1], l1);
            l2 = fmaf(h[j], Wor[j][2], l2);
        }
        const float m  = fmaxf(l0, fmaxf(l1, l2));
        const float e0 = __expf(l0 - m), e1 = __expf(l1 - m), e2 = __expf(l2 - m);
        const float rs = __builtin_amdgcn_rcpf(e0 + e1 + e2);
        const float p0 = e0 * rs, p1 = e1 * rs, p2 = e2 * rs;
        prow[t * LL + 0] = p0;
        prow[t * LL + 1] = p1;
        prow[t * LL + 2] = p2;

        // loss: labels are exact one-hot -> single log
        const int   y  = (la1 > 0.5f) ? 1 : ((la2 > 0.5f) ? 2 : 0);
        const float py = (y == 0) ? p0 : ((y == 1) ? p1 : p2);
        const float pc = fminf(fmaxf(py, 1e-7f), 1.0f);
        loss_acc -= __logf(pc);

        // accuracy: first-index-wins argmax (strict >)
        int ap = 0; float pm = p0;
        if (p1 > pm) { ap = 1; pm = p1; }
        if (p2 > pm) { ap = 2; }
        corr += (ap == y) ? 1 : 0;

        tk_cur = tk_nxt; la1 = lb1n; la2 = lb2n;
    }

    // wave(=block) reduction -> one partial per block (deterministic, no atomics)
    float ls = loss_acc;
    float cs = (float)corr;   // <= 6336 per wave, exact in f32
#pragma unroll
    for (int off = 32; off > 0; off >>= 1) {
        ls += __shfl_down(ls, off, 64);
        cs += __shfl_down(cs, off, 64);
    }
    if (threadIdx.x == 0) {
        ws[blockIdx.x]       = ls;
        ws[256 + blockIdx.x] = cs;
    }
}

__global__ __launch_bounds__(256)
void finalize_kernel(const float* __restrict__ ws, float* __restrict__ out_tail)
{
    __shared__ float sl[4], sc[4];
    const int t = threadIdx.x;
    float ls = ws[t];
    float cs = ws[256 + t];
#pragma unroll
    for (int off = 32; off > 0; off >>= 1) {
        ls += __shfl_down(ls, off, 64);
        cs += __shfl_down(cs, off, 64);
    }
    if ((t & 63) == 0) { sl[t >> 6] = ls; sc[t >> 6] = cs; }
    __syncthreads();
    if (t == 0) {
        const float L = sl[0] + sl[1] + sl[2] + sl[3];
        const float C = sc[0] + sc[1] + sc[2] + sc[3];
        const float inv = 1.0f / (float)((size_t)BB * TT);
        out_tail[0] = C * inv;   // accuracy
        out_tail[1] = L * inv;   // loss
    }
}

extern "C" void kernel_launch(void* const* d_in, const int* in_sizes, int n_in,
                              void* d_out, int out_size, void* d_ws, size_t ws_size,
                              hipStream_t stream)
{
    const int*   tok    = (const int*)  d_in[0];
    const float* labels = (const float*)d_in[1];
    // d_in[2] = mask (unused by reference math)
    const float* emb = (const float*)d_in[3];
    const float* W   = (const float*)d_in[4];
    const float* U   = (const float*)d_in[5];
    const float* bv  = (const float*)d_in[6];
    const float* Wo  = (const float*)d_in[7];
    const float* bo  = (const float*)d_in[8];

    float* out    = (float*)d_out;
    float* states = out;                                  // [B,T,10]
    float* probs  = out + (size_t)BB * TT * RR;           // [B,T,3]
    float* tail   = out + (size_t)BB * TT * (RR + LL);    // accuracy, loss
    float* ws     = (float*)d_ws;                         // 512 floats used

    rnn_fused_kernel<<<BB / 64, 64, 0, stream>>>(tok, labels, emb, W, U, bv, Wo, bo,
                                                 states, probs, ws);
    finalize_kernel<<<1, 256, 0, stream>>>(ws, tail);
}